// Round 9
// baseline (147.888 us; speedup 1.0000x reference)
//
#include <hip/hip_runtime.h>
#include <stdint.h>

#define BB 8192
#define DD 128
#define MARGIN 1.0f
#define CCAP 48
#define NBLK_POS (BB / 4)
#define NCH 16             // chunks (blocks) per row-panel
#define CHCOLS (BB / NCH)  // 512 cols per chunk
#define TPC (CHCOLS / 64)  // 8 B-tiles of 64 cols

typedef __attribute__((ext_vector_type(8))) short short8_t;
typedef __attribute__((ext_vector_type(4))) float f32x4;

// async global->LDS, 16B per lane; LDS dest is wave-uniform base + lane*16
#define GLL16(g, l)                                                                   \
  __builtin_amdgcn_global_load_lds(                                                   \
      (const __attribute__((address_space(1))) unsigned int*)(g),                     \
      (__attribute__((address_space(3))) unsigned int*)(l), 16, 0, 0)

#define KEEP(x) asm volatile("" ::"v"(x))

__device__ __forceinline__ unsigned short f2bf(float f) {
  unsigned u = __float_as_uint(f);
  u = (u + 0x7fffu + ((u >> 16) & 1u)) >> 16;  // RNE
  return (unsigned short)u;
}

// ---------------- Kernel 0: bf16 convert + sqnorm + bucket ----------------
__global__ void prep_kernel(const float* __restrict__ E, const int* __restrict__ lab,
                            unsigned short* __restrict__ Ebf,
                            float* __restrict__ sq,
                            int* __restrict__ cls_cnt, int* __restrict__ cls_idx) {
  int wid = threadIdx.x >> 6, lane = threadIdx.x & 63;
  int row = blockIdx.x * 4 + wid;
  const float2 v = *(const float2*)(E + (size_t)row * DD + lane * 2);
  ushort2 bb;
  bb.x = f2bf(v.x);
  bb.y = f2bf(v.y);
  *(ushort2*)(Ebf + (size_t)row * DD + lane * 2) = bb;
  float s = v.x * v.x + v.y * v.y;
  for (int off = 1; off < 64; off <<= 1) s += __shfl_xor(s, off);
  if (lane == 0) {
    sq[row] = s;
    int labi = lab[row];
    int p = atomicAdd(&cls_cnt[labi], 1);
    if (p < CCAP) cls_idx[labi * CCAP + p] = row;
  }
}

// ---------------- Kernel 1: masked-min distance GEMM ----------------
// Block (p,c): rows [p*128,+128) x cols [c*512,+512).
// A fragments in registers (16B global gathers, pinned via keep-alive +
// memory-clobber waitcnt). B: 2-deep global_load_lds pipeline with COUNTED
// vmcnt(4) + raw s_barrier (never drain-to-0 mid-loop).
// t[i] = min_j (0.5*sq_j - dot) masked lab_j != lab_i; plain stores.
__global__ __launch_bounds__(256, 3) void dist_min_kernel(
    const unsigned short* __restrict__ Ebf, const float* __restrict__ sq,
    const int* __restrict__ lab, float* __restrict__ part) {
  __shared__ __align__(16) char ldsB[2][64 * 256];  // 2 x 16 KB, swizzled
  __shared__ int labC[CHCOLS];
  __shared__ float hC[CHCOLS];
  __shared__ int labI[128];
  __shared__ float redMin[4][64];

  const int tid = threadIdx.x;
  const int p = blockIdx.x >> 4, c = blockIdx.x & (NCH - 1);
  const int rI = p * 128;
  const int cBase = c * CHCOLS;

  const int wid = tid >> 6, lane = tid & 63;
  const int l4 = lane >> 4, c16 = lane & 15;
  const int wr = wid >> 1, wc = wid & 1;
  const int rowbase = wr * 64;
  const int cl = c16, rg = l4;

  // ---- A fragments straight to registers (issued first; overlap with B stages)
  short8_t a[4][4];
#pragma unroll
  for (int m = 0; m < 4; m++) {
    const char* rowp = (const char*)Ebf + (size_t)(rI + rowbase + m * 16 + cl) * 256 + rg * 16;
#pragma unroll
    for (int kk = 0; kk < 4; kk++) a[m][kk] = *(const short8_t*)(rowp + kk * 64);
  }

// ---- stage macro: B tile tt -> LDS buffer (inverse-swizzled source) ----
#define STAGE_B(tt, buf)                                                            \
  {                                                                                 \
    _Pragma("unroll") for (int q = 0; q < 4; q++) {                                 \
      int r = wid * 16 + q * 4 + l4;                                                \
      int chunk = c16 ^ (r & 7);                                                    \
      GLL16((const char*)Ebf + (size_t)(cBase + (tt)*64 + r) * 256 + chunk * 16,    \
            (buf) + wid * 4096 + q * 1024);                                         \
    }                                                                               \
  }

  // ---- 2-deep prologue: B0, B1 in flight ----
  STAGE_B(0, ldsB[0]);
  STAGE_B(1, ldsB[1]);

  // column/row metadata (LDS writes; drained by lgkmcnt at first wait)
  for (int q = tid; q < CHCOLS; q += 256) {
    labC[q] = lab[cBase + q];
    hC[q] = 0.5f * sq[cBase + q];
  }
  if (tid < 128) labI[tid] = lab[rI + tid];

  // pin A values (prevents load sinking into the loop)
#pragma unroll
  for (int m = 0; m < 4; m++)
#pragma unroll
    for (int kk = 0; kk < 4; kk++) KEEP(a[m][kk]);

  int il[4][4];
  float tm[4][4];
#pragma unroll
  for (int m = 0; m < 4; m++)
#pragma unroll
    for (int r = 0; r < 4; r++) tm[m][r] = __builtin_huge_valf();

#pragma unroll
  for (int t = 0; t < TPC; t++) {
    // wait for stage(t) (leave stage(t+1)'s 4 loads in flight), sync block
    if (t < TPC - 1)
      asm volatile("s_waitcnt vmcnt(4) lgkmcnt(0)" ::: "memory");
    else
      asm volatile("s_waitcnt vmcnt(0) lgkmcnt(0)" ::: "memory");
    __builtin_amdgcn_sched_barrier(0);
    __builtin_amdgcn_s_barrier();
    __builtin_amdgcn_sched_barrier(0);

    if (t == 0) {
#pragma unroll
      for (int m = 0; m < 4; m++)
#pragma unroll
        for (int r = 0; r < 4; r++) il[m][r] = labI[rowbase + m * 16 + rg * 4 + r];
    }

    int jl[2];
    float jh[2];
#pragma unroll
    for (int n = 0; n < 2; n++) {
      int j = t * 64 + wc * 32 + n * 16 + cl;
      jl[n] = labC[j];
      jh[n] = hC[j];
    }

    f32x4 acc[4][2];
#pragma unroll
    for (int m = 0; m < 4; m++)
#pragma unroll
      for (int n = 0; n < 2; n++) acc[m][n] = (f32x4){0.f, 0.f, 0.f, 0.f};

#pragma unroll
    for (int kk = 0; kk < 4; kk++) {
      const int kb = kk * 64 + rg * 16;
      short8_t b[2];
#pragma unroll
      for (int n = 0; n < 2; n++) {
        int row = wc * 32 + n * 16 + cl;
        b[n] = *(const short8_t*)(ldsB[t & 1] + row * 256 + (kb ^ ((row & 7) << 4)));
      }
#pragma unroll
      for (int m = 0; m < 4; m++)
#pragma unroll
        for (int n = 0; n < 2; n++)
          acc[m][n] = __builtin_amdgcn_mfma_f32_16x16x32_bf16(a[m][kk], b[n], acc[m][n], 0, 0, 0);
    }

    // register fold: masked running min
#pragma unroll
    for (int m = 0; m < 4; m++)
#pragma unroll
      for (int n = 0; n < 2; n++) {
        f32x4 v = acc[m][n];
#pragma unroll
        for (int r = 0; r < 4; r++) {
          float u = jh[n] - v[r];
          if (il[m][r] != jl[n]) tm[m][r] = fminf(tm[m][r], u);
        }
      }

    // all waves done reading ldsB[t&1] -> safe to overwrite with stage(t+2)
    __builtin_amdgcn_s_barrier();
    __builtin_amdgcn_sched_barrier(0);
    if (t + 2 < TPC) STAGE_B(t + 2, ldsB[t & 1]);
  }

  // reduce across the 16 lanes sharing the same rows
#pragma unroll
  for (int m = 0; m < 4; m++)
#pragma unroll
    for (int r = 0; r < 4; r++) {
      float t = tm[m][r];
      t = fminf(t, __shfl_xor(t, 1));
      t = fminf(t, __shfl_xor(t, 2));
      t = fminf(t, __shfl_xor(t, 4));
      t = fminf(t, __shfl_xor(t, 8));
      tm[m][r] = t;
    }
  if (cl == 0) {
#pragma unroll
    for (int m = 0; m < 4; m++)
#pragma unroll
      for (int r = 0; r < 4; r++) redMin[wid][m * 16 + rg * 4 + r] = tm[m][r];
  }
  __syncthreads();
  if (wc == 0) {
    float v = fminf(redMin[wid][lane], redMin[wid + 1][lane]);
    part[(size_t)c * BB + rI + rowbase + lane] = v;
  }
}

// ---------------- Kernel 2: positives + hardest-neg fold, exact fp32 ----------------
__global__ void pos_loss_kernel(const float* __restrict__ E, const int* __restrict__ lab,
                                const float* __restrict__ sq, const float* __restrict__ part,
                                const int* __restrict__ cls_cnt, const int* __restrict__ cls_idx,
                                float* __restrict__ ptot, int* __restrict__ pcnt) {
  __shared__ float stot[4];
  __shared__ int scnt[4];
  const int tid = threadIdx.x, wid = tid >> 6, lane = tid & 63;
  const int i = blockIdx.x * 4 + wid;
  const int labi = lab[i];
  int n = cls_cnt[labi];
  if (n > CCAP) n = CCAP;
  const float2 ei = *(const float2*)(E + (size_t)i * DD + lane * 2);
  const float sqi = sq[i];
  float mn = __builtin_huge_valf();
#pragma unroll
  for (int cc = 0; cc < NCH; cc++) mn = fminf(mn, part[(size_t)cc * BB + i]);
  const float hn = fmaxf(sqi + 2.0f * mn, 0.0f);  // relu(min raw d)
  float tsum = 0.0f;
  int tcnt = 0;
  for (int s = 0; s < n; s++) {
    int j = cls_idx[labi * CCAP + s];
    if (j == i) continue;
    float2 ej = *(const float2*)(E + (size_t)j * DD + lane * 2);
    float pp = ei.x * ej.x + ei.y * ej.y;
    for (int off = 1; off < 64; off <<= 1) pp += __shfl_xor(pp, off);
    float d = fmaxf(sqi + sq[j] - 2.0f * pp, 0.0f);
    if (hn < d) {
      tcnt++;
      tsum += d - hn + MARGIN;
    }
  }
  if (lane == 0) {
    stot[wid] = tsum;
    scnt[wid] = tcnt;
  }
  __syncthreads();
  if (tid == 0) {
    ptot[blockIdx.x] = stot[0] + stot[1] + stot[2] + stot[3];
    pcnt[blockIdx.x] = scnt[0] + scnt[1] + scnt[2] + scnt[3];
  }
}

// ---------------- Kernel 3: reduce partials + finalize ----------------
__global__ void finalize_kernel(const float* __restrict__ ptot, const int* __restrict__ pcnt,
                                float* __restrict__ out) {
  __shared__ float stot[4];
  __shared__ int scnt[4];
  const int tid = threadIdx.x, wid = tid >> 6, lane = tid & 63;
  float t = 0.0f;
  int c = 0;
  for (int k = tid; k < NBLK_POS; k += 256) {
    t += ptot[k];
    c += pcnt[k];
  }
  for (int off = 1; off < 64; off <<= 1) {
    t += __shfl_xor(t, off);
    c += __shfl_xor(c, off);
  }
  if (lane == 0) {
    stot[wid] = t;
    scnt[wid] = c;
  }
  __syncthreads();
  if (tid == 0) {
    float tt = stot[0] + stot[1] + stot[2] + stot[3];
    int cc = scnt[0] + scnt[1] + scnt[2] + scnt[3];
    out[0] = tt / (float)(cc > 0 ? cc : 1);
    out[1] = (float)cc;
  }
}

extern "C" void kernel_launch(void* const* d_in, const int* in_sizes, int n_in,
                              void* d_out, int out_size, void* d_ws, size_t ws_size,
                              hipStream_t stream) {
  const float* E = (const float*)d_in[0];
  const int* lab = (const int*)d_in[1];
  float* out = (float*)d_out;

  char* ws = (char*)d_ws;
  unsigned short* Ebf = (unsigned short*)ws;                 // 2 MB
  float* sq = (float*)(ws + (size_t)BB * DD * 2);            // 32 KB
  int* cls_cnt = (int*)((char*)sq + BB * 4);                 // 4 KB (zeroed)
  int* cls_idx = (int*)((char*)cls_cnt + 1024 * 4);          // 192 KB
  float* ptot = (float*)((char*)cls_idx + 1024 * CCAP * 4);  // 8 KB
  int* pcnt = (int*)((char*)ptot + NBLK_POS * 4);            // 8 KB
  float* part = (float*)((char*)pcnt + NBLK_POS * 4);        // 512 KB

  hipMemsetAsync(cls_cnt, 0, 1024 * 4, stream);
  prep_kernel<<<BB / 4, 256, 0, stream>>>(E, lab, Ebf, sq, cls_cnt, cls_idx);
  dist_min_kernel<<<64 * NCH, 256, 0, stream>>>(Ebf, sq, lab, part);
  pos_loss_kernel<<<NBLK_POS, 256, 0, stream>>>(E, lab, sq, part, cls_cnt, cls_idx, ptot, pcnt);
  finalize_kernel<<<1, 256, 0, stream>>>(ptot, pcnt, out);
}

// Round 10
// 112.662 us; speedup vs baseline: 1.3127x; 1.3127x over previous
//
#include <hip/hip_runtime.h>
#include <stdint.h>

#define BB 8192
#define DD 128
#define MARGIN 1.0f
#define CCAP 48
#define NBLK_POS (BB / 4)
#define NCH 16             // chunks (blocks) per row-panel
#define CHCOLS (BB / NCH)  // 512 cols per chunk
#define TPC (CHCOLS / 64)  // 8 B-tiles of 64 cols

typedef __attribute__((ext_vector_type(8))) short short8_t;
typedef __attribute__((ext_vector_type(4))) float f32x4;

// async global->LDS, 16B per lane; LDS dest is wave-uniform base + lane*16
#define GLL16(g, l)                                                                   \
  __builtin_amdgcn_global_load_lds(                                                   \
      (const __attribute__((address_space(1))) unsigned int*)(g),                     \
      (__attribute__((address_space(3))) unsigned int*)(l), 16, 0, 0)

__device__ __forceinline__ unsigned short f2bf(float f) {
  unsigned u = __float_as_uint(f);
  u = (u + 0x7fffu + ((u >> 16) & 1u)) >> 16;  // RNE
  return (unsigned short)u;
}

// ---------------- Kernel 0: bf16 convert + sqnorm + bucket ----------------
__global__ void prep_kernel(const float* __restrict__ E, const int* __restrict__ lab,
                            unsigned short* __restrict__ Ebf,
                            float* __restrict__ sq,
                            int* __restrict__ cls_cnt, int* __restrict__ cls_idx) {
  int wid = threadIdx.x >> 6, lane = threadIdx.x & 63;
  int row = blockIdx.x * 4 + wid;
  const float2 v = *(const float2*)(E + (size_t)row * DD + lane * 2);
  ushort2 bb;
  bb.x = f2bf(v.x);
  bb.y = f2bf(v.y);
  *(ushort2*)(Ebf + (size_t)row * DD + lane * 2) = bb;
  float s = v.x * v.x + v.y * v.y;
  for (int off = 1; off < 64; off <<= 1) s += __shfl_xor(s, off);
  if (lane == 0) {
    sq[row] = s;
    int labi = lab[row];
    int p = atomicAdd(&cls_cnt[labi], 1);
    if (p < CCAP) cls_idx[labi * CCAP + p] = row;
  }
}

// ---------------- Kernel 1: masked-min distance GEMM ----------------
// Block (p,c): rows [p*128,+128) x cols [c*512,+512).
// A staged ONCE to LDS via global_load_lds (R7 structure, VGPR-safe).
// B: 2-deep global_load_lds double-buffer with COUNTED vmcnt(4) + raw
// s_barrier — prefetch stays in flight across barriers (T4), never
// drain-to-0 mid-loop. t[i] = min_j (0.5*sq_j - dot), lab_j != lab_i,
// register fold, plain stores. No atomics.
__global__ __launch_bounds__(256) void dist_min_kernel(
    const unsigned short* __restrict__ Ebf, const float* __restrict__ sq,
    const int* __restrict__ lab, float* __restrict__ part) {
  __shared__ __align__(16) char ldsA[128 * 256];    // 32 KB, swizzled
  __shared__ __align__(16) char ldsB[2][64 * 256];  // 2 x 16 KB, swizzled
  __shared__ int labC[CHCOLS];
  __shared__ float hC[CHCOLS];
  __shared__ int labI[128];
  __shared__ float redMin[4][64];

  const int tid = threadIdx.x;
  const int p = blockIdx.x >> 4, c = blockIdx.x & (NCH - 1);
  const int rI = p * 128;
  const int cBase = c * CHCOLS;

  const int wid = tid >> 6, lane = tid & 63;
  const int l4 = lane >> 4, c16 = lane & 15;
  const int wr = wid >> 1, wc = wid & 1;
  const int rowbase = wr * 64;
  const int cl = c16, rg = l4;

// ---- stage macros (inverse-swizzled source, linear LDS dest) ----
#define STAGE_A()                                                                   \
  {                                                                                 \
    _Pragma("unroll") for (int q = 0; q < 8; q++) {                                 \
      int r = wid * 32 + q * 4 + l4;                                                \
      int chunk = c16 ^ (r & 7);                                                    \
      GLL16((const char*)Ebf + (size_t)(rI + r) * 256 + chunk * 16,                 \
            ldsA + wid * 8192 + q * 1024);                                          \
    }                                                                               \
  }
#define STAGE_B(tt, buf)                                                            \
  {                                                                                 \
    _Pragma("unroll") for (int q = 0; q < 4; q++) {                                 \
      int r = wid * 16 + q * 4 + l4;                                                \
      int chunk = c16 ^ (r & 7);                                                    \
      GLL16((const char*)Ebf + (size_t)(cBase + (tt)*64 + r) * 256 + chunk * 16,    \
            (buf) + wid * 4096 + q * 1024);                                         \
    }                                                                               \
  }

  // ---- prologue: A (8) + B0 (4) + B1 (4) in flight = 16 per wave ----
  STAGE_A();
  STAGE_B(0, ldsB[0]);
  STAGE_B(1, ldsB[1]);

  // metadata via plain LDS stores (drained by lgkmcnt at tile 0)
  for (int q = tid; q < CHCOLS; q += 256) {
    labC[q] = lab[cBase + q];
    hC[q] = 0.5f * sq[cBase + q];
  }
  if (tid < 128) labI[tid] = lab[rI + tid];

  int il[4][4];
  float tm[4][4];
#pragma unroll
  for (int m = 0; m < 4; m++)
#pragma unroll
    for (int r = 0; r < 4; r++) tm[m][r] = __builtin_huge_valf();

#pragma unroll
  for (int t = 0; t < TPC; t++) {
    // release stage(t) [+A at t=0], keep stage(t+1) in flight
    if (t < TPC - 1)
      asm volatile("s_waitcnt vmcnt(4) lgkmcnt(0)" ::: "memory");
    else
      asm volatile("s_waitcnt vmcnt(0) lgkmcnt(0)" ::: "memory");
    __builtin_amdgcn_sched_barrier(0);
    __builtin_amdgcn_s_barrier();
    __builtin_amdgcn_sched_barrier(0);

    if (t == 0) {
#pragma unroll
      for (int m = 0; m < 4; m++)
#pragma unroll
        for (int r = 0; r < 4; r++) il[m][r] = labI[rowbase + m * 16 + rg * 4 + r];
    }

    int jl[2];
    float jh[2];
#pragma unroll
    for (int n = 0; n < 2; n++) {
      int j = t * 64 + wc * 32 + n * 16 + cl;
      jl[n] = labC[j];
      jh[n] = hC[j];
    }

    f32x4 acc[4][2];
#pragma unroll
    for (int m = 0; m < 4; m++)
#pragma unroll
      for (int n = 0; n < 2; n++) acc[m][n] = (f32x4){0.f, 0.f, 0.f, 0.f};

#pragma unroll
    for (int kk = 0; kk < 4; kk++) {
      const int kb = kk * 64 + rg * 16;
      short8_t a[4], b[2];
#pragma unroll
      for (int m = 0; m < 4; m++) {
        int row = rowbase + m * 16 + cl;
        a[m] = *(const short8_t*)(ldsA + row * 256 + (kb ^ ((row & 7) << 4)));
      }
#pragma unroll
      for (int n = 0; n < 2; n++) {
        int row = wc * 32 + n * 16 + cl;
        b[n] = *(const short8_t*)(ldsB[t & 1] + row * 256 + (kb ^ ((row & 7) << 4)));
      }
#pragma unroll
      for (int m = 0; m < 4; m++)
#pragma unroll
        for (int n = 0; n < 2; n++)
          acc[m][n] = __builtin_amdgcn_mfma_f32_16x16x32_bf16(a[m], b[n], acc[m][n], 0, 0, 0);
    }

    // register fold: masked running min
#pragma unroll
    for (int m = 0; m < 4; m++)
#pragma unroll
      for (int n = 0; n < 2; n++) {
        f32x4 v = acc[m][n];
#pragma unroll
        for (int r = 0; r < 4; r++) {
          float u = jh[n] - v[r];
          if (il[m][r] != jl[n]) tm[m][r] = fminf(tm[m][r], u);
        }
      }

    // all waves done reading ldsB[t&1] -> safe to overwrite with stage(t+2)
    __builtin_amdgcn_s_barrier();
    __builtin_amdgcn_sched_barrier(0);
    if (t + 2 < TPC) STAGE_B(t + 2, ldsB[t & 1]);
  }

  // reduce across the 16 lanes sharing the same rows
#pragma unroll
  for (int m = 0; m < 4; m++)
#pragma unroll
    for (int r = 0; r < 4; r++) {
      float t = tm[m][r];
      t = fminf(t, __shfl_xor(t, 1));
      t = fminf(t, __shfl_xor(t, 2));
      t = fminf(t, __shfl_xor(t, 4));
      t = fminf(t, __shfl_xor(t, 8));
      tm[m][r] = t;
    }
  if (cl == 0) {
#pragma unroll
    for (int m = 0; m < 4; m++)
#pragma unroll
      for (int r = 0; r < 4; r++) redMin[wid][m * 16 + rg * 4 + r] = tm[m][r];
  }
  __syncthreads();
  if (wc == 0) {
    float v = fminf(redMin[wid][lane], redMin[wid + 1][lane]);
    part[(size_t)c * BB + rI + rowbase + lane] = v;
  }
}

// ---------------- Kernel 2: positives + hardest-neg fold, exact fp32 ----------------
__global__ void pos_loss_kernel(const float* __restrict__ E, const int* __restrict__ lab,
                                const float* __restrict__ sq, const float* __restrict__ part,
                                const int* __restrict__ cls_cnt, const int* __restrict__ cls_idx,
                                float* __restrict__ ptot, int* __restrict__ pcnt) {
  __shared__ float stot[4];
  __shared__ int scnt[4];
  const int tid = threadIdx.x, wid = tid >> 6, lane = tid & 63;
  const int i = blockIdx.x * 4 + wid;
  const int labi = lab[i];
  int n = cls_cnt[labi];
  if (n > CCAP) n = CCAP;
  const float2 ei = *(const float2*)(E + (size_t)i * DD + lane * 2);
  const float sqi = sq[i];
  float mn = __builtin_huge_valf();
#pragma unroll
  for (int cc = 0; cc < NCH; cc++) mn = fminf(mn, part[(size_t)cc * BB + i]);
  const float hn = fmaxf(sqi + 2.0f * mn, 0.0f);  // relu(min raw d)
  float tsum = 0.0f;
  int tcnt = 0;
  for (int s = 0; s < n; s++) {
    int j = cls_idx[labi * CCAP + s];
    if (j == i) continue;
    float2 ej = *(const float2*)(E + (size_t)j * DD + lane * 2);
    float pp = ei.x * ej.x + ei.y * ej.y;
    for (int off = 1; off < 64; off <<= 1) pp += __shfl_xor(pp, off);
    float d = fmaxf(sqi + sq[j] - 2.0f * pp, 0.0f);
    if (hn < d) {
      tcnt++;
      tsum += d - hn + MARGIN;
    }
  }
  if (lane == 0) {
    stot[wid] = tsum;
    scnt[wid] = tcnt;
  }
  __syncthreads();
  if (tid == 0) {
    ptot[blockIdx.x] = stot[0] + stot[1] + stot[2] + stot[3];
    pcnt[blockIdx.x] = scnt[0] + scnt[1] + scnt[2] + scnt[3];
  }
}

// ---------------- Kernel 3: reduce partials + finalize ----------------
__global__ void finalize_kernel(const float* __restrict__ ptot, const int* __restrict__ pcnt,
                                float* __restrict__ out) {
  __shared__ float stot[4];
  __shared__ int scnt[4];
  const int tid = threadIdx.x, wid = tid >> 6, lane = tid & 63;
  float t = 0.0f;
  int c = 0;
  for (int k = tid; k < NBLK_POS; k += 256) {
    t += ptot[k];
    c += pcnt[k];
  }
  for (int off = 1; off < 64; off <<= 1) {
    t += __shfl_xor(t, off);
    c += __shfl_xor(c, off);
  }
  if (lane == 0) {
    stot[wid] = t;
    scnt[wid] = c;
  }
  __syncthreads();
  if (tid == 0) {
    float tt = stot[0] + stot[1] + stot[2] + stot[3];
    int cc = scnt[0] + scnt[1] + scnt[2] + scnt[3];
    out[0] = tt / (float)(cc > 0 ? cc : 1);
    out[1] = (float)cc;
  }
}

extern "C" void kernel_launch(void* const* d_in, const int* in_sizes, int n_in,
                              void* d_out, int out_size, void* d_ws, size_t ws_size,
                              hipStream_t stream) {
  const float* E = (const float*)d_in[0];
  const int* lab = (const int*)d_in[1];
  float* out = (float*)d_out;

  char* ws = (char*)d_ws;
  unsigned short* Ebf = (unsigned short*)ws;                 // 2 MB
  float* sq = (float*)(ws + (size_t)BB * DD * 2);            // 32 KB
  int* cls_cnt = (int*)((char*)sq + BB * 4);                 // 4 KB (zeroed)
  int* cls_idx = (int*)((char*)cls_cnt + 1024 * 4);          // 192 KB
  float* ptot = (float*)((char*)cls_idx + 1024 * CCAP * 4);  // 8 KB
  int* pcnt = (int*)((char*)ptot + NBLK_POS * 4);            // 8 KB
  float* part = (float*)((char*)pcnt + NBLK_POS * 4);        // 512 KB

  hipMemsetAsync(cls_cnt, 0, 1024 * 4, stream);
  prep_kernel<<<BB / 4, 256, 0, stream>>>(E, lab, Ebf, sq, cls_cnt, cls_idx);
  dist_min_kernel<<<64 * NCH, 256, 0, stream>>>(Ebf, sq, lab, part);
  pos_loss_kernel<<<NBLK_POS, 256, 0, stream>>>(E, lab, sq, part, cls_cnt, cls_idx, ptot, pcnt);
  finalize_kernel<<<1, 256, 0, stream>>>(ptot, pcnt, out);
}

// Round 11
// 112.144 us; speedup vs baseline: 1.3187x; 1.0046x over previous
//
#include <hip/hip_runtime.h>
#include <stdint.h>

#define BB 8192
#define DD 128
#define MARGIN 1.0f
#define CCAP 48
#define NBLK_POS (BB / 4)
#define NCH 16             // chunks (blocks) per row-panel
#define CHCOLS (BB / NCH)  // 512 cols per chunk
#define TPC (CHCOLS / 64)  // 8 B-tiles of 64 cols

typedef __attribute__((ext_vector_type(8))) short short8_t;
typedef __attribute__((ext_vector_type(4))) float f32x4;

// async global->LDS, 16B per lane; LDS dest is wave-uniform base + lane*16
#define GLL16(g, l)                                                                   \
  __builtin_amdgcn_global_load_lds(                                                   \
      (const __attribute__((address_space(1))) unsigned int*)(g),                     \
      (__attribute__((address_space(3))) unsigned int*)(l), 16, 0, 0)

__device__ __forceinline__ unsigned short f2bf(float f) {
  unsigned u = __float_as_uint(f);
  u = (u + 0x7fffu + ((u >> 16) & 1u)) >> 16;  // RNE
  return (unsigned short)u;
}

// ---------------- Kernel 0: bf16 convert + sqnorm + bucket ----------------
__global__ void prep_kernel(const float* __restrict__ E, const int* __restrict__ lab,
                            unsigned short* __restrict__ Ebf,
                            float* __restrict__ sq,
                            int* __restrict__ cls_cnt, int* __restrict__ cls_idx) {
  int wid = threadIdx.x >> 6, lane = threadIdx.x & 63;
  int row = blockIdx.x * 4 + wid;
  const float2 v = *(const float2*)(E + (size_t)row * DD + lane * 2);
  ushort2 bb;
  bb.x = f2bf(v.x);
  bb.y = f2bf(v.y);
  *(ushort2*)(Ebf + (size_t)row * DD + lane * 2) = bb;
  float s = v.x * v.x + v.y * v.y;
  for (int off = 1; off < 64; off <<= 1) s += __shfl_xor(s, off);
  if (lane == 0) {
    sq[row] = s;
    int labi = lab[row];
    int p = atomicAdd(&cls_cnt[labi], 1);
    if (p < CCAP) cls_idx[labi * CCAP + p] = row;
  }
}

// ---------------- Kernel 1: masked-min distance GEMM ----------------
// Block (p,c): rows [p*128,+128) x cols [c*512,+512).
// XCD-aware swizzle (T1): dispatch round-robins blockIdx%8 across XCDs, so
// map c = (bid&7) + 8*((bid>>3)&1), p = bid>>4-equivalent — all 128 blocks
// sharing a col-chunk land on ONE XCD -> B-chunk becomes a same-XCD L2 hit
// (cross-die traffic ~160 MB -> ~18 MB). Rest identical to R10:
// A staged once via global_load_lds; B 2-deep dbuf, counted vmcnt(4) + raw
// s_barrier (never drain-to-0 mid-loop). Register min-fold, plain stores.
__global__ __launch_bounds__(256) void dist_min_kernel(
    const unsigned short* __restrict__ Ebf, const float* __restrict__ sq,
    const int* __restrict__ lab, float* __restrict__ part) {
  __shared__ __align__(16) char ldsA[128 * 256];    // 32 KB, swizzled
  __shared__ __align__(16) char ldsB[2][64 * 256];  // 2 x 16 KB, swizzled
  __shared__ int labC[CHCOLS];
  __shared__ float hC[CHCOLS];
  __shared__ int labI[128];
  __shared__ float redMin[4][64];

  const int tid = threadIdx.x;
  // T1 swizzle: bijective (bid in [0,1024)) -> (p in [0,64), c in [0,16))
  const int bid = blockIdx.x;
  const int xcd = bid & 7, slot = bid >> 3;
  const int c = xcd + 8 * (slot & 1);
  const int p = slot >> 1;
  const int rI = p * 128;
  const int cBase = c * CHCOLS;

  const int wid = tid >> 6, lane = tid & 63;
  const int l4 = lane >> 4, c16 = lane & 15;
  const int wr = wid >> 1, wc = wid & 1;
  const int rowbase = wr * 64;
  const int cl = c16, rg = l4;

// ---- stage macros (inverse-swizzled source, linear LDS dest) ----
#define STAGE_A()                                                                   \
  {                                                                                 \
    _Pragma("unroll") for (int q = 0; q < 8; q++) {                                 \
      int r = wid * 32 + q * 4 + l4;                                                \
      int chunk = c16 ^ (r & 7);                                                    \
      GLL16((const char*)Ebf + (size_t)(rI + r) * 256 + chunk * 16,                 \
            ldsA + wid * 8192 + q * 1024);                                          \
    }                                                                               \
  }
#define STAGE_B(tt, buf)                                                            \
  {                                                                                 \
    _Pragma("unroll") for (int q = 0; q < 4; q++) {                                 \
      int r = wid * 16 + q * 4 + l4;                                                \
      int chunk = c16 ^ (r & 7);                                                    \
      GLL16((const char*)Ebf + (size_t)(cBase + (tt)*64 + r) * 256 + chunk * 16,    \
            (buf) + wid * 4096 + q * 1024);                                         \
    }                                                                               \
  }

  // ---- prologue: A (8) + B0 (4) + B1 (4) in flight = 16 per wave ----
  STAGE_A();
  STAGE_B(0, ldsB[0]);
  STAGE_B(1, ldsB[1]);

  // metadata via plain LDS stores (drained by lgkmcnt at tile 0)
  for (int q = tid; q < CHCOLS; q += 256) {
    labC[q] = lab[cBase + q];
    hC[q] = 0.5f * sq[cBase + q];
  }
  if (tid < 128) labI[tid] = lab[rI + tid];

  int il[4][4];
  float tm[4][4];
#pragma unroll
  for (int m = 0; m < 4; m++)
#pragma unroll
    for (int r = 0; r < 4; r++) tm[m][r] = __builtin_huge_valf();

#pragma unroll
  for (int t = 0; t < TPC; t++) {
    // release stage(t) [+A at t=0], keep stage(t+1) in flight
    if (t < TPC - 1)
      asm volatile("s_waitcnt vmcnt(4) lgkmcnt(0)" ::: "memory");
    else
      asm volatile("s_waitcnt vmcnt(0) lgkmcnt(0)" ::: "memory");
    __builtin_amdgcn_sched_barrier(0);
    __builtin_amdgcn_s_barrier();
    __builtin_amdgcn_sched_barrier(0);

    if (t == 0) {
#pragma unroll
      for (int m = 0; m < 4; m++)
#pragma unroll
        for (int r = 0; r < 4; r++) il[m][r] = labI[rowbase + m * 16 + rg * 4 + r];
    }

    int jl[2];
    float jh[2];
#pragma unroll
    for (int n = 0; n < 2; n++) {
      int j = t * 64 + wc * 32 + n * 16 + cl;
      jl[n] = labC[j];
      jh[n] = hC[j];
    }

    f32x4 acc[4][2];
#pragma unroll
    for (int m = 0; m < 4; m++)
#pragma unroll
      for (int n = 0; n < 2; n++) acc[m][n] = (f32x4){0.f, 0.f, 0.f, 0.f};

#pragma unroll
    for (int kk = 0; kk < 4; kk++) {
      const int kb = kk * 64 + rg * 16;
      short8_t a[4], b[2];
#pragma unroll
      for (int m = 0; m < 4; m++) {
        int row = rowbase + m * 16 + cl;
        a[m] = *(const short8_t*)(ldsA + row * 256 + (kb ^ ((row & 7) << 4)));
      }
#pragma unroll
      for (int n = 0; n < 2; n++) {
        int row = wc * 32 + n * 16 + cl;
        b[n] = *(const short8_t*)(ldsB[t & 1] + row * 256 + (kb ^ ((row & 7) << 4)));
      }
#pragma unroll
      for (int m = 0; m < 4; m++)
#pragma unroll
        for (int n = 0; n < 2; n++)
          acc[m][n] = __builtin_amdgcn_mfma_f32_16x16x32_bf16(a[m], b[n], acc[m][n], 0, 0, 0);
    }

    // register fold: masked running min
#pragma unroll
    for (int m = 0; m < 4; m++)
#pragma unroll
      for (int n = 0; n < 2; n++) {
        f32x4 v = acc[m][n];
#pragma unroll
        for (int r = 0; r < 4; r++) {
          float u = jh[n] - v[r];
          if (il[m][r] != jl[n]) tm[m][r] = fminf(tm[m][r], u);
        }
      }

    // all waves done reading ldsB[t&1] -> safe to overwrite with stage(t+2)
    __builtin_amdgcn_s_barrier();
    __builtin_amdgcn_sched_barrier(0);
    if (t + 2 < TPC) STAGE_B(t + 2, ldsB[t & 1]);
  }

  // reduce across the 16 lanes sharing the same rows
#pragma unroll
  for (int m = 0; m < 4; m++)
#pragma unroll
    for (int r = 0; r < 4; r++) {
      float t = tm[m][r];
      t = fminf(t, __shfl_xor(t, 1));
      t = fminf(t, __shfl_xor(t, 2));
      t = fminf(t, __shfl_xor(t, 4));
      t = fminf(t, __shfl_xor(t, 8));
      tm[m][r] = t;
    }
  if (cl == 0) {
#pragma unroll
    for (int m = 0; m < 4; m++)
#pragma unroll
      for (int r = 0; r < 4; r++) redMin[wid][m * 16 + rg * 4 + r] = tm[m][r];
  }
  __syncthreads();
  if (wc == 0) {
    float v = fminf(redMin[wid][lane], redMin[wid + 1][lane]);
    part[(size_t)c * BB + rI + rowbase + lane] = v;
  }
}

// ---------------- Kernel 2: positives + hardest-neg fold, exact fp32 ----------------
__global__ void pos_loss_kernel(const float* __restrict__ E, const int* __restrict__ lab,
                                const float* __restrict__ sq, const float* __restrict__ part,
                                const int* __restrict__ cls_cnt, const int* __restrict__ cls_idx,
                                float* __restrict__ ptot, int* __restrict__ pcnt) {
  __shared__ float stot[4];
  __shared__ int scnt[4];
  const int tid = threadIdx.x, wid = tid >> 6, lane = tid & 63;
  const int i = blockIdx.x * 4 + wid;
  const int labi = lab[i];
  int n = cls_cnt[labi];
  if (n > CCAP) n = CCAP;
  const float2 ei = *(const float2*)(E + (size_t)i * DD + lane * 2);
  const float sqi = sq[i];
  float mn = __builtin_huge_valf();
#pragma unroll
  for (int cc = 0; cc < NCH; cc++) mn = fminf(mn, part[(size_t)cc * BB + i]);
  const float hn = fmaxf(sqi + 2.0f * mn, 0.0f);  // relu(min raw d)
  float tsum = 0.0f;
  int tcnt = 0;
  for (int s = 0; s < n; s++) {
    int j = cls_idx[labi * CCAP + s];
    if (j == i) continue;
    float2 ej = *(const float2*)(E + (size_t)j * DD + lane * 2);
    float pp = ei.x * ej.x + ei.y * ej.y;
    for (int off = 1; off < 64; off <<= 1) pp += __shfl_xor(pp, off);
    float d = fmaxf(sqi + sq[j] - 2.0f * pp, 0.0f);
    if (hn < d) {
      tcnt++;
      tsum += d - hn + MARGIN;
    }
  }
  if (lane == 0) {
    stot[wid] = tsum;
    scnt[wid] = tcnt;
  }
  __syncthreads();
  if (tid == 0) {
    ptot[blockIdx.x] = stot[0] + stot[1] + stot[2] + stot[3];
    pcnt[blockIdx.x] = scnt[0] + scnt[1] + scnt[2] + scnt[3];
  }
}

// ---------------- Kernel 3: reduce partials + finalize ----------------
__global__ void finalize_kernel(const float* __restrict__ ptot, const int* __restrict__ pcnt,
                                float* __restrict__ out) {
  __shared__ float stot[4];
  __shared__ int scnt[4];
  const int tid = threadIdx.x, wid = tid >> 6, lane = tid & 63;
  float t = 0.0f;
  int c = 0;
  for (int k = tid; k < NBLK_POS; k += 256) {
    t += ptot[k];
    c += pcnt[k];
  }
  for (int off = 1; off < 64; off <<= 1) {
    t += __shfl_xor(t, off);
    c += __shfl_xor(c, off);
  }
  if (lane == 0) {
    stot[wid] = t;
    scnt[wid] = c;
  }
  __syncthreads();
  if (tid == 0) {
    float tt = stot[0] + stot[1] + stot[2] + stot[3];
    int cc = scnt[0] + scnt[1] + scnt[2] + scnt[3];
    out[0] = tt / (float)(cc > 0 ? cc : 1);
    out[1] = (float)cc;
  }
}

extern "C" void kernel_launch(void* const* d_in, const int* in_sizes, int n_in,
                              void* d_out, int out_size, void* d_ws, size_t ws_size,
                              hipStream_t stream) {
  const float* E = (const float*)d_in[0];
  const int* lab = (const int*)d_in[1];
  float* out = (float*)d_out;

  char* ws = (char*)d_ws;
  unsigned short* Ebf = (unsigned short*)ws;                 // 2 MB
  float* sq = (float*)(ws + (size_t)BB * DD * 2);            // 32 KB
  int* cls_cnt = (int*)((char*)sq + BB * 4);                 // 4 KB (zeroed)
  int* cls_idx = (int*)((char*)cls_cnt + 1024 * 4);          // 192 KB
  float* ptot = (float*)((char*)cls_idx + 1024 * CCAP * 4);  // 8 KB
  int* pcnt = (int*)((char*)ptot + NBLK_POS * 4);            // 8 KB
  float* part = (float*)((char*)pcnt + NBLK_POS * 4);        // 512 KB

  hipMemsetAsync(cls_cnt, 0, 1024 * 4, stream);
  prep_kernel<<<BB / 4, 256, 0, stream>>>(E, lab, Ebf, sq, cls_cnt, cls_idx);
  dist_min_kernel<<<64 * NCH, 256, 0, stream>>>(Ebf, sq, lab, part);
  pos_loss_kernel<<<NBLK_POS, 256, 0, stream>>>(E, lab, sq, part, cls_cnt, cls_idx, ptot, pcnt);
  finalize_kernel<<<1, 256, 0, stream>>>(ptot, pcnt, out);
}